// Round 3
// baseline (366.219 us; speedup 1.0000x reference)
//
#include <hip/hip_runtime.h>
#include <hip/hip_bf16.h>
#include <hip/hip_cooperative_groups.h>

namespace cg = cooperative_groups;

using bf16 = __hip_bfloat16;

typedef _Float16 half1;
typedef _Float16 half2_t __attribute__((ext_vector_type(2)));

#define K 25
#define D0 7200
#define D1 3600
#define D2 1800

// pk stream word bases: [L0ch0][L0ch1][L1ch0][L1ch1][L2ch0][L2ch1], layout [k][d]
// pk word = (input_byte_offset << 16) | fp16(weight)  (idx pre-scaled by 4)
#define PKB_L1 360000
#define PKB_L2 540000
#define NPK    630000
// pbias layout: [L0ch0][L0ch1][L1ch0][L1ch1][L2ch0][L2ch1] (25200 entries)
#define NPB    25200

#define NT 1024   // threads per fused block (16 waves/CU; LDS caps blocks/CU at 1)
#define GRID 256  // one block per CU — cooperative co-residency holds

__device__ __forceinline__ float b2f(ushort u) {
  unsigned int w = ((unsigned int)u) << 16;
  float f; __builtin_memcpy(&f, &w, 4); return f;
}
__device__ __forceinline__ ushort f2b(float f) {
  bf16 h = __float2bfloat16(f);
  ushort u; __builtin_memcpy(&u, &h, 2); return u;
}
__device__ __forceinline__ ushort f2h(float f) {
  half1 h = (half1)f;
  return __builtin_bit_cast(ushort, h);
}
__device__ __forceinline__ unsigned int pkf16(float a, float b) {
  return __builtin_bit_cast(unsigned int, __builtin_amdgcn_cvt_pkrtz(a, b));
}

// ---------------------------------------------------------------------------
// Shared building block: map gid -> (layer, ch, d) and write pk/pbias.
// ---------------------------------------------------------------------------
__device__ __forceinline__ void prepack_one(
    int gid, int idt, int fdt,
    const void* knn0, const void* knn1, const void* knn2,
    const void* wp0, const void* bp0, const void* wp1, const void* bp1,
    const void* wp2, const void* bp2,
    const void* wn0, const void* bn0, const void* wn1, const void* bn1,
    const void* wn2, const void* bn2,
    unsigned int* __restrict__ pk, float* __restrict__ pbias) {
  int i = gid, d, dout, pkb;
  const void *kn, *wsel, *bsel;
  if (i < 14400) {
    const int ch = i / D0; d = i - ch * D0; dout = D0;
    pkb = ch * 180000; kn = knn0;
    wsel = ch ? wn0 : wp0; bsel = ch ? bn0 : bp0;
  } else if (i < 21600) {
    i -= 14400; const int ch = i / D1; d = i - ch * D1; dout = D1;
    pkb = PKB_L1 + ch * 90000; kn = knn1;
    wsel = ch ? wn1 : wp1; bsel = ch ? bn1 : bp1;
  } else {
    i -= 21600; const int ch = i / D2; d = i - ch * D2; dout = D2;
    pkb = PKB_L2 + ch * 45000; kn = knn2;
    wsel = ch ? wn2 : wp2; bsel = ch ? bn2 : bp2;
  }
  const int pos0 = d * K;
#pragma unroll
  for (int k = 0; k < K; ++k) {
    const unsigned int idx = idt ? ((const unsigned int*)kn)[2 * (pos0 + k)]
                                 : ((const unsigned int*)kn)[pos0 + k];
    const ushort wb = fdt ? f2h(b2f(((const ushort*)wsel)[pos0 + k]))
                          : f2h(((const float*)wsel)[pos0 + k]);
    pk[pkb + k * dout + d] = (idx << 18) | (unsigned int)wb;
  }
  pbias[gid] = fdt ? b2f(((const ushort*)bsel)[d]) : ((const float*)bsel)[d];
}

// ---------------------------------------------------------------------------
// One LCN layer inside LDS: out[d][0..1] = relu(sum_k w * in[idx][0..1] + b)
// lds holds activations as [f] half2 (one 4B word per feature, 2 batch rows).
// pk layout [k][d]: lanes (consecutive d) load coalesced per k.
// ---------------------------------------------------------------------------
template <int BIN, int BOUT>
__device__ __forceinline__ void layer_run(char* ldsb, const unsigned int* __restrict__ pk,
                                          const float* __restrict__ pbias,
                                          int pkb, int pbb, int dout) {
  for (int d = threadIdx.x; d < dout; d += NT) {
    const int base = pkb + d;
    float a0 = 0.f, a1 = 0.f;
#pragma unroll
    for (int k = 0; k < K; ++k) {
      const unsigned int pw = pk[base + k * dout];
      const half2_t vv = *(const half2_t*)(ldsb + BIN + (pw >> 16));
      const half1 wh = __builtin_bit_cast(half1, (ushort)(pw & 0xFFFFu));
      a0 = fmaf((float)wh, (float)vv.x, a0);
      a1 = fmaf((float)wh, (float)vv.y, a1);
    }
    const float bias = pbias[pbb + d];
    a0 = fmaxf(a0 + bias, 0.f);
    a1 = fmaxf(a1 + bias, 0.f);
    *(unsigned int*)(ldsb + BOUT + (d << 2)) = pkf16(a0, a1);
  }
}

// ---------------------------------------------------------------------------
// Staging helper: input rows b0, b0+1 (channel's 14400 features) -> half2 LDS.
// ---------------------------------------------------------------------------
__device__ __forceinline__ void stage_x(char* ldsb, const void* __restrict__ x,
                                        int fdt, int ch, int b0) {
  const int t = threadIdx.x;
  if (fdt) {
    const ushort* r0 = (const ushort*)x + (size_t)b0 * 28800 + ch * 14400;
    const ushort* r1 = r0 + 28800;
    for (int c = t; c < 3600; c += NT) {
      const ushort4 a = ((const ushort4*)r0)[c];
      const ushort4 b = ((const ushort4*)r1)[c];
      uint4 u;
      u.x = pkf16(b2f(a.x), b2f(b.x));
      u.y = pkf16(b2f(a.y), b2f(b.y));
      u.z = pkf16(b2f(a.z), b2f(b.z));
      u.w = pkf16(b2f(a.w), b2f(b.w));
      ((uint4*)ldsb)[c] = u;
    }
  } else {
    const float* r0 = (const float*)x + (size_t)b0 * 28800 + ch * 14400;
    const float* r1 = r0 + 28800;
    for (int c = t; c < 3600; c += NT) {
      const float4 a = ((const float4*)r0)[c];
      const float4 b = ((const float4*)r1)[c];
      uint4 u;
      u.x = pkf16(a.x, b.x);
      u.y = pkf16(a.y, b.y);
      u.z = pkf16(a.z, b.z);
      u.w = pkf16(a.w, b.w);
      ((uint4*)ldsb)[c] = u;
    }
  }
}

// ---------------------------------------------------------------------------
// Compute phase shared by merged and fallback kernels: 3 LCN layers + fc +
// atomic y reduce + last-done combine. Assumes x already staged in ldsb and
// pk/pbias visible.
// ---------------------------------------------------------------------------
__device__ __forceinline__ void compute_phase(
    char* ldsb, float (*red)[4], int* sflag_p,
    const unsigned int* __restrict__ pk, const float* __restrict__ pbias,
    const void* fcpw, const void* fcnw, const void* fcpb, const void* fcnb,
    const void* f3w, const void* f3b,
    float* __restrict__ y, int* __restrict__ flags, void* __restrict__ out,
    int fdt, int ch, int b0, int nblocks) {
  const int t = threadIdx.x;

  layer_run<0, 57600>(ldsb, pk, pbias, 0 + ch * 180000, 0 + ch * D0, D0);
  __syncthreads();
  layer_run<57600, 0>(ldsb, pk, pbias, PKB_L1 + ch * 90000, 14400 + ch * D1, D1);
  __syncthreads();
  layer_run<0, 14400>(ldsb, pk, pbias, PKB_L2 + ch * 45000, 21600 + ch * D2, D2);
  __syncthreads();

  // ---- fc: y[ch][o][b0..b0+1] = sum_d fw[o][d] * h2[d][.] ----
  {
    const void* fw = ch ? fcnw : fcpw;
    float a00 = 0.f, a01 = 0.f, a10 = 0.f, a11 = 0.f;
    for (int d = t; d < D2; d += NT) {
      const half2_t vv = *(const half2_t*)(ldsb + 14400 + (d << 2));
      const float v0 = (float)vv.x;
      const float v1 = (float)vv.y;
      const float w0 = fdt ? b2f(((const ushort*)fw)[d]) : ((const float*)fw)[d];
      const float w1 = fdt ? b2f(((const ushort*)fw)[D2 + d]) : ((const float*)fw)[D2 + d];
      a00 = fmaf(w0, v0, a00); a01 = fmaf(w0, v1, a01);
      a10 = fmaf(w1, v0, a10); a11 = fmaf(w1, v1, a11);
    }
#pragma unroll
    for (int off = 32; off > 0; off >>= 1) {
      a00 += __shfl_down(a00, off);
      a01 += __shfl_down(a01, off);
      a10 += __shfl_down(a10, off);
      a11 += __shfl_down(a11, off);
    }
    const int wave = t >> 6, lane = t & 63;
    if (lane == 0) {
      red[wave][0] = a00; red[wave][1] = a01; red[wave][2] = a10; red[wave][3] = a11;
    }
    __syncthreads();
    if (t == 0) {
      float s00 = 0.f, s01 = 0.f, s10 = 0.f, s11 = 0.f;
#pragma unroll
      for (int wv = 0; wv < NT / 64; ++wv) {
        s00 += red[wv][0]; s01 += red[wv][1]; s10 += red[wv][2]; s11 += red[wv][3];
      }
      atomicAdd(&y[(ch * 2 + 0) * 256 + b0], s00);
      atomicAdd(&y[(ch * 2 + 0) * 256 + b0 + 1], s01);
      atomicAdd(&y[(ch * 2 + 1) * 256 + b0], s10);
      atomicAdd(&y[(ch * 2 + 1) * 256 + b0 + 1], s11);
    }
  }

  // ---- last-done block computes the final combine (round-5-validated) ----
  __syncthreads();
  if (t == 0) {
    __threadfence();
    *sflag_p = (atomicAdd(&flags[16], 1) == nblocks - 1) ? 1 : 0;
  }
  __syncthreads();
  if (*sflag_p && t < 256) {
    const int b = t;
    const float y0 = atomicAdd(&y[0 * 256 + b], 0.0f);
    const float y1 = atomicAdd(&y[1 * 256 + b], 0.0f);
    const float y2 = atomicAdd(&y[2 * 256 + b], 0.0f);
    const float y3 = atomicAdd(&y[3 * 256 + b], 0.0f);
    const float bp0v = fdt ? b2f(((const ushort*)fcpb)[0]) : ((const float*)fcpb)[0];
    const float bp1v = fdt ? b2f(((const ushort*)fcpb)[1]) : ((const float*)fcpb)[1];
    const float bn0v = fdt ? b2f(((const ushort*)fcnb)[0]) : ((const float*)fcnb)[0];
    const float bn1v = fdt ? b2f(((const ushort*)fcnb)[1]) : ((const float*)fcnb)[1];
    const float h0v = fmaxf(y0 + bp0v, 0.f);
    const float h1v = fmaxf(y1 + bp1v, 0.f);
    const float h2v = fmaxf(y2 + bn0v, 0.f);
    const float h3v = fmaxf(y3 + bn1v, 0.f);
#pragma unroll
    for (int o = 0; o < 2; ++o) {
      float w0, w1, w2, w3, bb;
      if (fdt) {
        const ushort* fp = (const ushort*)f3w;
        w0 = b2f(fp[o * 4 + 0]); w1 = b2f(fp[o * 4 + 1]);
        w2 = b2f(fp[o * 4 + 2]); w3 = b2f(fp[o * 4 + 3]);
        bb = b2f(((const ushort*)f3b)[o]);
      } else {
        const float* fp = (const float*)f3w;
        w0 = fp[o * 4 + 0]; w1 = fp[o * 4 + 1];
        w2 = fp[o * 4 + 2]; w3 = fp[o * 4 + 3];
        bb = ((const float*)f3b)[o];
      }
      float r = bb;
      r = fmaf(w0, h0v, r); r = fmaf(w1, h1v, r);
      r = fmaf(w2, h2v, r); r = fmaf(w3, h3v, r);
      if (fdt) ((ushort*)out)[b * 2 + o] = f2b(r);
      else     ((float*)out)[b * 2 + o] = r;
    }
  }
}

// ===========================================================================
// MERGED cooperative kernel: per-block dtype vote -> prepack slice ->
// stage x -> grid.sync (device fences flush/invalidate non-coherent XCD L2)
// -> layers/fc/combine.  y zeroed via atomicExch (coherent point), so no
// kernel-boundary writeback is needed for it.
// ===========================================================================
__global__ __launch_bounds__(NT) void lcn_all(
    const void* __restrict__ x,
    const void* __restrict__ knn0, const void* __restrict__ knn1,
    const void* __restrict__ knn2,
    const void* __restrict__ wp0, const void* __restrict__ bp0,
    const void* __restrict__ wp1, const void* __restrict__ bp1,
    const void* __restrict__ wp2, const void* __restrict__ bp2,
    const void* __restrict__ wn0, const void* __restrict__ bn0,
    const void* __restrict__ wn1, const void* __restrict__ bn1,
    const void* __restrict__ wn2, const void* __restrict__ bn2,
    const void* __restrict__ fcpw, const void* __restrict__ fcnw,
    const void* __restrict__ fcpb, const void* __restrict__ fcnb,
    const void* __restrict__ f3w, const void* __restrict__ f3b,
    unsigned int* __restrict__ pk, float* __restrict__ pbias,
    float* __restrict__ y, int* __restrict__ flags, void* __restrict__ out) {
  __shared__ __align__(16) char ldsb[86400];
  __shared__ float red[NT / 64][4];
  __shared__ int s_flags[2];
  __shared__ int sflag;
  const int t = threadIdx.x;
  const int bid = blockIdx.x;
  const int ch = bid & 1;
  const int b0 = (bid >> 1) * 2;

  // ---- per-block dtype vote (validated pattern) ----
  if (t < 64) {
    const unsigned int u = ((const unsigned int*)x)[t * 997];
    const unsigned int e = (u >> 23) & 0xFF;
    const unsigned long long m = __ballot((e >= 192) || (e <= 30));
    if (t == 0) s_flags[0] = (__popcll(m) >= 32) ? 1 : 0;
  } else if (t < 128) {
    const int l = t - 64;
    const unsigned int hi = ((const unsigned int*)knn0)[2 * l + 1];
    const unsigned long long m = __ballot(hi != 0);
    if (l == 0) s_flags[1] = (m == 0ULL) ? 1 : 0;
  }
  __syncthreads();
  const int fdt = s_flags[0], idt = s_flags[1];

  // ---- phase A: prepack slice (blocks 0..24 active), bookkeeping ----
  const int gid = bid * NT + t;
  if (gid < NPB) {
    prepack_one(gid, idt, fdt, knn0, knn1, knn2,
                wp0, bp0, wp1, bp1, wp2, bp2,
                wn0, bn0, wn1, bn1, wn2, bn2, pk, pbias);
  }
  if (bid == GRID - 1) {
    atomicExch((unsigned int*)&y[t & 1023], 0u);  // t in [0,1024): zero all of y
    if (t == 0) atomicExch(&flags[16], 0);
  }

  // ---- stage x (overlaps other blocks' prepack) ----
  stage_x(ldsb, x, fdt, ch, b0);
  __syncthreads();

  // ---- grid-wide sync with device-scope fences (cross-XCD visibility) ----
  __threadfence();          // release: flush pk/pbias out of writer L2s
  cg::this_grid().sync();
  __threadfence();          // acquire: drop stale (poisoned) L2 lines

  compute_phase(ldsb, red, &sflag, pk, pbias, fcpw, fcnw, fcpb, fcnb,
                f3w, f3b, y, flags, out, fdt, ch, b0, GRID);
}

// ===========================================================================
// FALLBACK path (current passing two-kernel version) — used only if the
// cooperative launch is rejected (e.g., graph-capture incompatibility).
// ===========================================================================
__global__ __launch_bounds__(256) void prepack_kernel(
    const void* __restrict__ x,
    const void* __restrict__ knn0, const void* __restrict__ knn1,
    const void* __restrict__ knn2,
    const void* __restrict__ wp0, const void* __restrict__ bp0,
    const void* __restrict__ wp1, const void* __restrict__ bp1,
    const void* __restrict__ wp2, const void* __restrict__ bp2,
    const void* __restrict__ wn0, const void* __restrict__ bn0,
    const void* __restrict__ wn1, const void* __restrict__ bn1,
    const void* __restrict__ wn2, const void* __restrict__ bn2,
    unsigned int* __restrict__ pk, float* __restrict__ pbias,
    float* __restrict__ y, int* __restrict__ flags) {
  __shared__ int s_flags[2];
  const int t = threadIdx.x;
  if (t < 64) {
    const unsigned int u = ((const unsigned int*)x)[t * 997];
    const unsigned int e = (u >> 23) & 0xFF;
    const unsigned long long m = __ballot((e >= 192) || (e <= 30));
    if (t == 0) s_flags[0] = (__popcll(m) >= 32) ? 1 : 0;
  } else if (t < 128) {
    const int l = t - 64;
    const unsigned int hi = ((const unsigned int*)knn0)[2 * l + 1];
    const unsigned long long m = __ballot(hi != 0);
    if (l == 0) s_flags[1] = (m == 0ULL) ? 1 : 0;
  }
  __syncthreads();
  const int fdt = s_flags[0], idt = s_flags[1];

  if (blockIdx.x == 0 && t == 0) {
    flags[0] = fdt; flags[1] = idt; flags[16] = 0;
  }

  const int gid = blockIdx.x * 256 + t;
  if (gid < NPB) {
    prepack_one(gid, idt, fdt, knn0, knn1, knn2,
                wp0, bp0, wp1, bp1, wp2, bp2,
                wn0, bn0, wn1, bn1, wn2, bn2, pk, pbias);
  } else if (gid < NPB + 1024) {
    y[gid - NPB] = 0.0f;
  }
}

__global__ __launch_bounds__(NT) void lcn_fused(
    const void* __restrict__ x, const unsigned int* __restrict__ pk,
    const float* __restrict__ pbias,
    const void* __restrict__ fcpw, const void* __restrict__ fcnw,
    const void* __restrict__ fcpb, const void* __restrict__ fcnb,
    const void* __restrict__ f3w, const void* __restrict__ f3b,
    float* __restrict__ y, int* __restrict__ flags, void* __restrict__ out) {
  __shared__ __align__(16) char ldsb[86400];
  __shared__ float red[NT / 64][4];
  __shared__ int sflag;
  const int t = threadIdx.x;
  const int ch = blockIdx.x & 1;
  const int b0 = (blockIdx.x >> 1) * 2;

  if (t == 0) sflag = flags[0];
  __syncthreads();
  const int fdt = sflag;

  stage_x(ldsb, x, fdt, ch, b0);
  __syncthreads();

  compute_phase(ldsb, red, &sflag, pk, pbias, fcpw, fcnw, fcpb, fcnb,
                f3w, f3b, y, flags, out, fdt, ch, b0, (int)gridDim.x);
}

extern "C" void kernel_launch(void* const* d_in, const int* in_sizes, int n_in,
                              void* d_out, int out_size, void* d_ws, size_t ws_size,
                              hipStream_t stream) {
  const void* x    = d_in[0];
  const void* knn0 = d_in[1];
  const void* knn1 = d_in[2];
  const void* knn2 = d_in[3];
  const void* wp0  = d_in[4];  const void* bp0 = d_in[5];
  const void* wp1  = d_in[6];  const void* bp1 = d_in[7];
  const void* wp2  = d_in[8];  const void* bp2 = d_in[9];
  const void* fcpw = d_in[10]; const void* fcpb = d_in[11];
  const void* wn0  = d_in[12]; const void* bn0 = d_in[13];
  const void* wn1  = d_in[14]; const void* bn1 = d_in[15];
  const void* wn2  = d_in[16]; const void* bn2 = d_in[17];
  const void* fcnw = d_in[18]; const void* fcnb = d_in[19];
  const void* f3w  = d_in[20]; const void* f3b  = d_in[21];

  char* ws = (char*)d_ws;
  unsigned int* pk = (unsigned int*)(ws);         // 630000*4 = 2,520,000 B
  float* pbias = (float*)(ws + 2520000);          // 25200*4  =   100,800 B
  float* y     = (float*)(ws + 2620800);          // 1024*4   =     4,096 B
  int* flags   = (int*)(ws + 2624896);            // flags[0..1], flags[16]

  void* out = d_out;
  void* args[] = {
      (void*)&x, (void*)&knn0, (void*)&knn1, (void*)&knn2,
      (void*)&wp0, (void*)&bp0, (void*)&wp1, (void*)&bp1,
      (void*)&wp2, (void*)&bp2,
      (void*)&wn0, (void*)&bn0, (void*)&wn1, (void*)&bn1,
      (void*)&wn2, (void*)&bn2,
      (void*)&fcpw, (void*)&fcnw, (void*)&fcpb, (void*)&fcnb,
      (void*)&f3w, (void*)&f3b,
      (void*)&pk, (void*)&pbias, (void*)&y, (void*)&flags, (void*)&out};

  hipError_t e = hipLaunchCooperativeKernel((const void*)lcn_all, dim3(GRID),
                                            dim3(NT), args, 0, stream);
  if (e != hipSuccess) {
    // Fallback: validated two-kernel path (kernel boundary provides coherence)
    prepack_kernel<<<103, 256, 0, stream>>>(x, knn0, knn1, knn2,
                                            wp0, bp0, wp1, bp1, wp2, bp2,
                                            wn0, bn0, wn1, bn1, wn2, bn2,
                                            pk, pbias, y, flags);
    lcn_fused<<<256, NT, 0, stream>>>(x, pk, pbias, fcpw, fcnw, fcpb, fcnb,
                                      f3w, f3b, y, flags, d_out);
  }
}

// Round 4
// 174.394 us; speedup vs baseline: 2.1000x; 2.1000x over previous
//
#include <hip/hip_runtime.h>
#include <hip/hip_bf16.h>

using bf16 = __hip_bfloat16;

typedef _Float16 half1;
typedef _Float16 half2_t __attribute__((ext_vector_type(2)));

#define K 25
#define D0 7200
#define D1 3600
#define D2 1800

// pk stream word bases: [L0ch0][L0ch1][L1ch0][L1ch1][L2ch0][L2ch1], layout [k][d]
// pk word = (input_byte_offset << 16) | fp16(weight)  (idx pre-scaled by 4)
#define PKB_L1 360000
#define PKB_L2 540000
#define NPK    630000
// pbias layout: [L0ch0][L0ch1][L1ch0][L1ch1][L2ch0][L2ch1] (25200 entries)
#define NPB    25200

#define NT 1024   // threads per fused block (16 waves/CU; LDS caps blocks/CU at 1)

__device__ __forceinline__ float b2f(ushort u) {
  unsigned int w = ((unsigned int)u) << 16;
  float f; __builtin_memcpy(&f, &w, 4); return f;
}
__device__ __forceinline__ ushort f2b(float f) {
  bf16 h = __float2bfloat16(f);
  ushort u; __builtin_memcpy(&u, &h, 2); return u;
}
__device__ __forceinline__ ushort f2h(float f) {
  half1 h = (half1)f;
  return __builtin_bit_cast(ushort, h);
}
__device__ __forceinline__ unsigned int pkf16(float a, float b) {
  return __builtin_bit_cast(unsigned int, __builtin_amdgcn_cvt_pkrtz(a, b));
}

// ---------------------------------------------------------------------------
// gid -> (layer, ch, d) mapping shared by prepack threads.
// ---------------------------------------------------------------------------
struct DimMap {
  int d, dout, pkb;
  const void *kn, *wsel, *bsel;
};
__device__ __forceinline__ DimMap map_gid(
    int gid,
    const void* knn0, const void* knn1, const void* knn2,
    const void* wp0, const void* bp0, const void* wp1, const void* bp1,
    const void* wp2, const void* bp2,
    const void* wn0, const void* bn0, const void* wn1, const void* bn1,
    const void* wn2, const void* bn2) {
  DimMap m;
  int i = gid;
  if (i < 14400) {
    const int ch = i / D0; m.d = i - ch * D0; m.dout = D0;
    m.pkb = ch * 180000; m.kn = knn0;
    m.wsel = ch ? wn0 : wp0; m.bsel = ch ? bn0 : bp0;
  } else if (i < 21600) {
    i -= 14400; const int ch = i / D1; m.d = i - ch * D1; m.dout = D1;
    m.pkb = PKB_L1 + ch * 90000; m.kn = knn1;
    m.wsel = ch ? wn1 : wp1; m.bsel = ch ? bn1 : bp1;
  } else {
    i -= 21600; const int ch = i / D2; m.d = i - ch * D2; m.dout = D2;
    m.pkb = PKB_L2 + ch * 45000; m.kn = knn2;
    m.wsel = ch ? wn2 : wp2; m.bsel = ch ? bn2 : bp2;
  }
  return m;
}

// ---------------------------------------------------------------------------
// Prepack: k-loop split across 2 threads (13/12) -> 197 blocks of 256
// (128 dims/block x 2 khalves) to halve the dependent-load chain and double
// block parallelism vs the 103-block one-thread-per-dim version.
// Block 197 zeroes y. Dtype votes (validated r2-r8) per block.
// ---------------------------------------------------------------------------
__global__ __launch_bounds__(256) void prepack_kernel(
    const void* __restrict__ x,
    const void* __restrict__ knn0, const void* __restrict__ knn1,
    const void* __restrict__ knn2,
    const void* __restrict__ wp0, const void* __restrict__ bp0,
    const void* __restrict__ wp1, const void* __restrict__ bp1,
    const void* __restrict__ wp2, const void* __restrict__ bp2,
    const void* __restrict__ wn0, const void* __restrict__ bn0,
    const void* __restrict__ wn1, const void* __restrict__ bn1,
    const void* __restrict__ wn2, const void* __restrict__ bn2,
    unsigned int* __restrict__ pk, float* __restrict__ pbias,
    float* __restrict__ y, int* __restrict__ flags) {
  __shared__ int s_flags[2];
  const int t = threadIdx.x;

  if (blockIdx.x == 197) {  // y zero block (no votes needed)
    if (t < 256) {
#pragma unroll
      for (int j = 0; j < 4; ++j) y[t + j * 256] = 0.0f;
    }
    return;
  }

  // fdt=1 -> floats are bf16; idt=1 -> knn is int64
  if (t < 64) {
    const unsigned int u = ((const unsigned int*)x)[t * 997];
    const unsigned int e = (u >> 23) & 0xFF;
    const unsigned long long m = __ballot((e >= 192) || (e <= 30));
    if (t == 0) s_flags[0] = (__popcll(m) >= 32) ? 1 : 0;
  } else if (t < 128) {
    const int l = t - 64;
    const unsigned int hi = ((const unsigned int*)knn0)[2 * l + 1];
    const unsigned long long m = __ballot(hi != 0);
    if (l == 0) s_flags[1] = (m == 0ULL) ? 1 : 0;
  }
  __syncthreads();
  const int fdt = s_flags[0], idt = s_flags[1];

  if (blockIdx.x == 0 && t == 0) {
    flags[0] = fdt; flags[1] = idt; flags[16] = 0;
  }

  const int local = t & 127;
  const int khalf = t >> 7;
  const int gid = blockIdx.x * 128 + local;
  if (gid < NPB) {
    const DimMap m = map_gid(gid, knn0, knn1, knn2,
                             wp0, bp0, wp1, bp1, wp2, bp2,
                             wn0, bn0, wn1, bn1, wn2, bn2);
    const int pos0 = m.d * K;
    if (khalf == 0) {
#pragma unroll
      for (int k = 0; k < 13; ++k) {
        const unsigned int idx = idt ? ((const unsigned int*)m.kn)[2 * (pos0 + k)]
                                     : ((const unsigned int*)m.kn)[pos0 + k];
        const ushort wb = fdt ? f2h(b2f(((const ushort*)m.wsel)[pos0 + k]))
                              : f2h(((const float*)m.wsel)[pos0 + k]);
        pk[m.pkb + k * m.dout + m.d] = (idx << 18) | (unsigned int)wb;
      }
      pbias[gid] = fdt ? b2f(((const ushort*)m.bsel)[m.d]) : ((const float*)m.bsel)[m.d];
    } else {
#pragma unroll
      for (int k = 13; k < 25; ++k) {
        const unsigned int idx = idt ? ((const unsigned int*)m.kn)[2 * (pos0 + k)]
                                     : ((const unsigned int*)m.kn)[pos0 + k];
        const ushort wb = fdt ? f2h(b2f(((const ushort*)m.wsel)[pos0 + k]))
                              : f2h(((const float*)m.wsel)[pos0 + k]);
        pk[m.pkb + k * m.dout + m.d] = (idx << 18) | (unsigned int)wb;
      }
    }
  }
}

// ---------------------------------------------------------------------------
// One LCN layer inside LDS: out[d][0..1] = relu(sum_k w * in[idx][0..1] + b)
// lds holds activations as [f] half2 (one 4B word per feature, 2 batch rows).
// pk layout [k][d]: lanes (consecutive d) load coalesced per k.
// Unroll-2 over d (d, d+NT): 50 independent gathers in flight, 4 fma chains;
// DOUT templated so k*DOUT folds to compile-time address constants.
// Out-of-range second slot uses pw=0 -> gathers LDS[BIN+0], w=0 (no effect).
// ---------------------------------------------------------------------------
template <int BIN, int BOUT, int DOUT>
__device__ __forceinline__ void layer_run(char* ldsb, const unsigned int* __restrict__ pk,
                                          const float* __restrict__ pbias,
                                          int pkb, int pbb) {
  const int t = threadIdx.x;
  for (int d = t; d < DOUT; d += 2 * NT) {
    const int dB = d + NT;
    const bool hasB = dB < DOUT;
    const unsigned int* sA = pk + pkb + d;
    const unsigned int* sB = pk + pkb + dB;
    float a0 = 0.f, a1 = 0.f, c0 = 0.f, c1 = 0.f;
#pragma unroll
    for (int k = 0; k < K; ++k) {
      const unsigned int pwA = sA[k * DOUT];
      const unsigned int pwB = hasB ? sB[k * DOUT] : 0u;
      const half2_t vA = *(const half2_t*)(ldsb + BIN + (pwA >> 16));
      const half2_t vB = *(const half2_t*)(ldsb + BIN + (pwB >> 16));
      const half1 wA = __builtin_bit_cast(half1, (ushort)(pwA & 0xFFFFu));
      const half1 wB = __builtin_bit_cast(half1, (ushort)(pwB & 0xFFFFu));
      a0 = fmaf((float)wA, (float)vA.x, a0);
      a1 = fmaf((float)wA, (float)vA.y, a1);
      c0 = fmaf((float)wB, (float)vB.x, c0);
      c1 = fmaf((float)wB, (float)vB.y, c1);
    }
    const float biasA = pbias[pbb + d];
    a0 = fmaxf(a0 + biasA, 0.f);
    a1 = fmaxf(a1 + biasA, 0.f);
    *(unsigned int*)(ldsb + BOUT + (d << 2)) = pkf16(a0, a1);
    if (hasB) {
      const float biasB = pbias[pbb + dB];
      c0 = fmaxf(c0 + biasB, 0.f);
      c1 = fmaxf(c1 + biasB, 0.f);
      *(unsigned int*)(ldsb + BOUT + (dB << 2)) = pkf16(c0, c1);
    }
  }
}

// ---------------------------------------------------------------------------
// Staging helper: input rows b0, b0+1 (channel's 14400 features) -> half2 LDS.
// ---------------------------------------------------------------------------
__device__ __forceinline__ void stage_x(char* ldsb, const void* __restrict__ x,
                                        int fdt, int ch, int b0) {
  const int t = threadIdx.x;
  if (fdt) {
    const ushort* r0 = (const ushort*)x + (size_t)b0 * 28800 + ch * 14400;
    const ushort* r1 = r0 + 28800;
    for (int c = t; c < 3600; c += NT) {
      const ushort4 a = ((const ushort4*)r0)[c];
      const ushort4 b = ((const ushort4*)r1)[c];
      uint4 u;
      u.x = pkf16(b2f(a.x), b2f(b.x));
      u.y = pkf16(b2f(a.y), b2f(b.y));
      u.z = pkf16(b2f(a.z), b2f(b.z));
      u.w = pkf16(b2f(a.w), b2f(b.w));
      ((uint4*)ldsb)[c] = u;
    }
  } else {
    const float* r0 = (const float*)x + (size_t)b0 * 28800 + ch * 14400;
    const float* r1 = r0 + 28800;
    for (int c = t; c < 3600; c += NT) {
      const float4 a = ((const float4*)r0)[c];
      const float4 b = ((const float4*)r1)[c];
      uint4 u;
      u.x = pkf16(a.x, b.x);
      u.y = pkf16(a.y, b.y);
      u.z = pkf16(a.z, b.z);
      u.w = pkf16(a.w, b.w);
      ((uint4*)ldsb)[c] = u;
    }
  }
}

// ---------------------------------------------------------------------------
// Fused network: block = (channel, batch-slice of 2), NT=1024 (16 waves/CU).
// LDS plan (bytes, half2 per feature): in@0 (57600) -> h0@57600 (28800);
// L1: h0@57600 -> h1@0 (14400); L2: h1@0 -> h2@14400 (7200); fc reads h2@14400.
// __launch_bounds__(NT,4): VGPR capped at 128 so all 16 waves stay resident.
// ---------------------------------------------------------------------------
__global__ __launch_bounds__(NT, 4) void lcn_fused(
    const void* __restrict__ x, const unsigned int* __restrict__ pk,
    const float* __restrict__ pbias,
    const void* __restrict__ fcpw, const void* __restrict__ fcnw,
    const void* __restrict__ fcpb, const void* __restrict__ fcnb,
    const void* __restrict__ f3w, const void* __restrict__ f3b,
    float* __restrict__ y, int* __restrict__ flags, void* __restrict__ out) {
  __shared__ __align__(16) char ldsb[86400];
  __shared__ float red[NT / 64][4];
  __shared__ int sflag;
  const int t = threadIdx.x;
  const int ch = blockIdx.x & 1;
  const int b0 = (blockIdx.x >> 1) * 2;

  if (t == 0) sflag = flags[0];
  __syncthreads();
  const int fdt = sflag;

  stage_x(ldsb, x, fdt, ch, b0);
  __syncthreads();

  layer_run<0, 57600, D0>(ldsb, pk, pbias, 0 + ch * 180000, 0 + ch * D0);
  __syncthreads();
  layer_run<57600, 0, D1>(ldsb, pk, pbias, PKB_L1 + ch * 90000, 14400 + ch * D1);
  __syncthreads();
  layer_run<0, 14400, D2>(ldsb, pk, pbias, PKB_L2 + ch * 45000, 21600 + ch * D2);
  __syncthreads();

  // ---- fc: y[ch][o][b0..b0+1] = sum_d fw[o][d] * h2[d][.] ----
  {
    const void* fw = ch ? fcnw : fcpw;
    float a00 = 0.f, a01 = 0.f, a10 = 0.f, a11 = 0.f;
    for (int d = t; d < D2; d += NT) {
      const half2_t vv = *(const half2_t*)(ldsb + 14400 + (d << 2));
      const float v0 = (float)vv.x;
      const float v1 = (float)vv.y;
      const float w0 = fdt ? b2f(((const ushort*)fw)[d]) : ((const float*)fw)[d];
      const float w1 = fdt ? b2f(((const ushort*)fw)[D2 + d]) : ((const float*)fw)[D2 + d];
      a00 = fmaf(w0, v0, a00); a01 = fmaf(w0, v1, a01);
      a10 = fmaf(w1, v0, a10); a11 = fmaf(w1, v1, a11);
    }
#pragma unroll
    for (int off = 32; off > 0; off >>= 1) {
      a00 += __shfl_down(a00, off);
      a01 += __shfl_down(a01, off);
      a10 += __shfl_down(a10, off);
      a11 += __shfl_down(a11, off);
    }
    const int wave = t >> 6, lane = t & 63;
    if (lane == 0) {
      red[wave][0] = a00; red[wave][1] = a01; red[wave][2] = a10; red[wave][3] = a11;
    }
    __syncthreads();
    if (t == 0) {
      float s00 = 0.f, s01 = 0.f, s10 = 0.f, s11 = 0.f;
#pragma unroll
      for (int wv = 0; wv < NT / 64; ++wv) {
        s00 += red[wv][0]; s01 += red[wv][1]; s10 += red[wv][2]; s11 += red[wv][3];
      }
      atomicAdd(&y[(ch * 2 + 0) * 256 + b0], s00);
      atomicAdd(&y[(ch * 2 + 0) * 256 + b0 + 1], s01);
      atomicAdd(&y[(ch * 2 + 1) * 256 + b0], s10);
      atomicAdd(&y[(ch * 2 + 1) * 256 + b0 + 1], s11);
    }
  }

  // ---- last-done block computes the final combine (round-5-validated) ----
  __syncthreads();
  if (t == 0) {
    __threadfence();
    sflag = (atomicAdd(&flags[16], 1) == (int)gridDim.x - 1) ? 1 : 0;
  }
  __syncthreads();
  if (sflag && t < 256) {
    const int b = t;
    const float y0 = atomicAdd(&y[0 * 256 + b], 0.0f);
    const float y1 = atomicAdd(&y[1 * 256 + b], 0.0f);
    const float y2 = atomicAdd(&y[2 * 256 + b], 0.0f);
    const float y3 = atomicAdd(&y[3 * 256 + b], 0.0f);
    const float bp0v = fdt ? b2f(((const ushort*)fcpb)[0]) : ((const float*)fcpb)[0];
    const float bp1v = fdt ? b2f(((const ushort*)fcpb)[1]) : ((const float*)fcpb)[1];
    const float bn0v = fdt ? b2f(((const ushort*)fcnb)[0]) : ((const float*)fcnb)[0];
    const float bn1v = fdt ? b2f(((const ushort*)fcnb)[1]) : ((const float*)fcnb)[1];
    const float h0v = fmaxf(y0 + bp0v, 0.f);
    const float h1v = fmaxf(y1 + bp1v, 0.f);
    const float h2v = fmaxf(y2 + bn0v, 0.f);
    const float h3v = fmaxf(y3 + bn1v, 0.f);
#pragma unroll
    for (int o = 0; o < 2; ++o) {
      float w0, w1, w2, w3, bb;
      if (fdt) {
        const ushort* fp = (const ushort*)f3w;
        w0 = b2f(fp[o * 4 + 0]); w1 = b2f(fp[o * 4 + 1]);
        w2 = b2f(fp[o * 4 + 2]); w3 = b2f(fp[o * 4 + 3]);
        bb = b2f(((const ushort*)f3b)[o]);
      } else {
        const float* fp = (const float*)f3w;
        w0 = fp[o * 4 + 0]; w1 = fp[o * 4 + 1];
        w2 = fp[o * 4 + 2]; w3 = fp[o * 4 + 3];
        bb = ((const float*)f3b)[o];
      }
      float r = bb;
      r = fmaf(w0, h0v, r); r = fmaf(w1, h1v, r);
      r = fmaf(w2, h2v, r); r = fmaf(w3, h3v, r);
      if (fdt) ((ushort*)out)[b * 2 + o] = f2b(r);
      else     ((float*)out)[b * 2 + o] = r;
    }
  }
}

extern "C" void kernel_launch(void* const* d_in, const int* in_sizes, int n_in,
                              void* d_out, int out_size, void* d_ws, size_t ws_size,
                              hipStream_t stream) {
  const void* x    = d_in[0];
  const void* knn0 = d_in[1];
  const void* knn1 = d_in[2];
  const void* knn2 = d_in[3];
  const void* wp0  = d_in[4];  const void* bp0 = d_in[5];
  const void* wp1  = d_in[6];  const void* bp1 = d_in[7];
  const void* wp2  = d_in[8];  const void* bp2 = d_in[9];
  const void* fcpw = d_in[10]; const void* fcpb = d_in[11];
  const void* wn0  = d_in[12]; const void* bn0 = d_in[13];
  const void* wn1  = d_in[14]; const void* bn1 = d_in[15];
  const void* wn2  = d_in[16]; const void* bn2 = d_in[17];
  const void* fcnw = d_in[18]; const void* fcnb = d_in[19];
  const void* f3w  = d_in[20]; const void* f3b  = d_in[21];

  char* ws = (char*)d_ws;
  unsigned int* pk = (unsigned int*)(ws);         // 630000*4 = 2,520,000 B
  float* pbias = (float*)(ws + 2520000);          // 25200*4  =   100,800 B
  float* y     = (float*)(ws + 2620800);          // 1024*4   =     4,096 B
  int* flags   = (int*)(ws + 2624896);            // flags[0..1], flags[16]

  // 197 prepack blocks (128 dims x 2 khalves each) + 1 y-zero block
  prepack_kernel<<<198, 256, 0, stream>>>(x, knn0, knn1, knn2,
                                          wp0, bp0, wp1, bp1, wp2, bp2,
                                          wn0, bn0, wn1, bn1, wn2, bn2,
                                          pk, pbias, y, flags);

  lcn_fused<<<256, NT, 0, stream>>>(x, pk, pbias, fcpw, fcnw, fcpb, fcnb,
                                    f3w, f3b, y, flags, d_out);
}

// Round 5
// 144.494 us; speedup vs baseline: 2.5345x; 1.2069x over previous
//
#include <hip/hip_runtime.h>
#include <hip/hip_bf16.h>

using bf16 = __hip_bfloat16;

typedef _Float16 half1;
typedef _Float16 half2_t __attribute__((ext_vector_type(2)));

#define K 25
#define D0 7200
#define D1 3600
#define D2 1800

// pk stream word bases: [L0ch0][L0ch1][L1ch0][L1ch1][L2ch0][L2ch1], layout [k][slot]
// slot pairing: dim d -> slot 2d (d<half) or 2(d-half)+1, so (d, d+half) is one
// aligned uint2.  pk word = (input_byte_offset << 16) | fp16(weight).
#define PKB_L1 360000
#define PKB_L2 540000
#define NPK    630000
// pbias layout: [L0ch0][L0ch1][L1ch0][L1ch1][L2ch0][L2ch1] (25200 entries)
#define NPB    25200

#define NT 1024   // threads per fused block (16 waves/CU; LDS caps blocks/CU at 1)

__device__ __forceinline__ float b2f(ushort u) {
  unsigned int w = ((unsigned int)u) << 16;
  float f; __builtin_memcpy(&f, &w, 4); return f;
}
__device__ __forceinline__ ushort f2b(float f) {
  bf16 h = __float2bfloat16(f);
  ushort u; __builtin_memcpy(&u, &h, 2); return u;
}
__device__ __forceinline__ ushort f2h(float f) {
  half1 h = (half1)f;
  return __builtin_bit_cast(ushort, h);
}
__device__ __forceinline__ unsigned int pkf16(float a, float b) {
  return __builtin_bit_cast(unsigned int, __builtin_amdgcn_cvt_pkrtz(a, b));
}

// ---------------------------------------------------------------------------
// gid -> (layer, ch, d) mapping shared by prepack threads.
// ---------------------------------------------------------------------------
struct DimMap {
  int d, dout, pkb;
  const void *kn, *wsel, *bsel;
};
__device__ __forceinline__ DimMap map_gid(
    int gid,
    const void* knn0, const void* knn1, const void* knn2,
    const void* wp0, const void* bp0, const void* wp1, const void* bp1,
    const void* wp2, const void* bp2,
    const void* wn0, const void* bn0, const void* wn1, const void* bn1,
    const void* wn2, const void* bn2) {
  DimMap m;
  int i = gid;
  if (i < 14400) {
    const int ch = i / D0; m.d = i - ch * D0; m.dout = D0;
    m.pkb = ch * 180000; m.kn = knn0;
    m.wsel = ch ? wn0 : wp0; m.bsel = ch ? bn0 : bp0;
  } else if (i < 21600) {
    i -= 14400; const int ch = i / D1; m.d = i - ch * D1; m.dout = D1;
    m.pkb = PKB_L1 + ch * 90000; m.kn = knn1;
    m.wsel = ch ? wn1 : wp1; m.bsel = ch ? bn1 : bp1;
  } else {
    i -= 21600; const int ch = i / D2; m.d = i - ch * D2; m.dout = D2;
    m.pkb = PKB_L2 + ch * 45000; m.kn = knn2;
    m.wsel = ch ? wn2 : wp2; m.bsel = ch ? bn2 : bp2;
  }
  return m;
}

// ---------------------------------------------------------------------------
// Prepack: k-loop split across 2 threads (13/12) -> 197 blocks of 256
// (128 dims/block x 2 khalves). Writes the PAIRED slot layout (see top).
// Block 197 zeroes y. Dtype votes (validated r2-r8) per block.
// ---------------------------------------------------------------------------
__global__ __launch_bounds__(256) void prepack_kernel(
    const void* __restrict__ x,
    const void* __restrict__ knn0, const void* __restrict__ knn1,
    const void* __restrict__ knn2,
    const void* __restrict__ wp0, const void* __restrict__ bp0,
    const void* __restrict__ wp1, const void* __restrict__ bp1,
    const void* __restrict__ wp2, const void* __restrict__ bp2,
    const void* __restrict__ wn0, const void* __restrict__ bn0,
    const void* __restrict__ wn1, const void* __restrict__ bn1,
    const void* __restrict__ wn2, const void* __restrict__ bn2,
    unsigned int* __restrict__ pk, float* __restrict__ pbias,
    float* __restrict__ y, int* __restrict__ flags) {
  __shared__ int s_flags[2];
  const int t = threadIdx.x;

  if (blockIdx.x == 197) {  // y zero block (no votes needed)
    if (t < 256) {
#pragma unroll
      for (int j = 0; j < 4; ++j) y[t + j * 256] = 0.0f;
    }
    return;
  }

  // fdt=1 -> floats are bf16; idt=1 -> knn is int64
  if (t < 64) {
    const unsigned int u = ((const unsigned int*)x)[t * 997];
    const unsigned int e = (u >> 23) & 0xFF;
    const unsigned long long m = __ballot((e >= 192) || (e <= 30));
    if (t == 0) s_flags[0] = (__popcll(m) >= 32) ? 1 : 0;
  } else if (t < 128) {
    const int l = t - 64;
    const unsigned int hi = ((const unsigned int*)knn0)[2 * l + 1];
    const unsigned long long m = __ballot(hi != 0);
    if (l == 0) s_flags[1] = (m == 0ULL) ? 1 : 0;
  }
  __syncthreads();
  const int fdt = s_flags[0], idt = s_flags[1];

  if (blockIdx.x == 0 && t == 0) {
    flags[0] = fdt; flags[1] = idt; flags[16] = 0;
  }

  const int local = t & 127;
  const int khalf = t >> 7;
  const int gid = blockIdx.x * 128 + local;
  if (gid < NPB) {
    const DimMap m = map_gid(gid, knn0, knn1, knn2,
                             wp0, bp0, wp1, bp1, wp2, bp2,
                             wn0, bn0, wn1, bn1, wn2, bn2);
    const int half = m.dout >> 1;
    const int slot = (m.d < half) ? (m.d << 1) : (((m.d - half) << 1) | 1);
    const int pos0 = m.d * K;
    const int k0 = khalf ? 13 : 0;
    const int k1 = khalf ? 25 : 13;
    for (int k = k0; k < k1; ++k) {
      const unsigned int idx = idt ? ((const unsigned int*)m.kn)[2 * (pos0 + k)]
                                   : ((const unsigned int*)m.kn)[pos0 + k];
      const ushort wb = fdt ? f2h(b2f(((const ushort*)m.wsel)[pos0 + k]))
                            : f2h(((const float*)m.wsel)[pos0 + k]);
      pk[m.pkb + k * m.dout + slot] = (idx << 18) | (unsigned int)wb;
    }
    if (khalf == 0) {
      pbias[gid] = fdt ? b2f(((const ushort*)m.bsel)[m.d]) : ((const float*)m.bsel)[m.d];
    }
  }
}

// ---------------------------------------------------------------------------
// One LCN layer inside LDS: out[d][0..1] = relu(sum_k w * in[idx][0..1] + b)
// lds holds activations as [f] half2 (one 4B word per feature, 2 batch rows).
// Branch-free unroll-2: thread handles dims (d, d+DOUT/2); the pk pair is one
// aligned uint2 (paired slot layout) -> per k: 1 global_load_dwordx2,
// 2 independent ds_read_b32 gathers, 4 independent fma chains. No
// conditionals in the body, so the compiler can software-pipeline across d.
// ---------------------------------------------------------------------------
template <int BIN, int BOUT, int DOUT>
__device__ __forceinline__ void layer_run(char* ldsb, const unsigned int* __restrict__ pk,
                                          const float* __restrict__ pbias,
                                          int pkb, int pbb) {
  constexpr int HALF = DOUT / 2;
  for (int d = threadIdx.x; d < HALF; d += NT) {
    const unsigned int* s = pk + pkb + (d << 1);
    float a0 = 0.f, a1 = 0.f, c0 = 0.f, c1 = 0.f;
#pragma unroll
    for (int k = 0; k < K; ++k) {
      const uint2 pw = *(const uint2*)(s + k * DOUT);
      const half2_t vA = *(const half2_t*)(ldsb + BIN + (pw.x >> 16));
      const half2_t vB = *(const half2_t*)(ldsb + BIN + (pw.y >> 16));
      const half1 wA = __builtin_bit_cast(half1, (ushort)(pw.x & 0xFFFFu));
      const half1 wB = __builtin_bit_cast(half1, (ushort)(pw.y & 0xFFFFu));
      a0 = fmaf((float)wA, (float)vA.x, a0);
      a1 = fmaf((float)wA, (float)vA.y, a1);
      c0 = fmaf((float)wB, (float)vB.x, c0);
      c1 = fmaf((float)wB, (float)vB.y, c1);
    }
    const float bA = pbias[pbb + d];
    const float bB = pbias[pbb + d + HALF];
    a0 = fmaxf(a0 + bA, 0.f);
    a1 = fmaxf(a1 + bA, 0.f);
    c0 = fmaxf(c0 + bB, 0.f);
    c1 = fmaxf(c1 + bB, 0.f);
    *(unsigned int*)(ldsb + BOUT + (d << 2)) = pkf16(a0, a1);
    *(unsigned int*)(ldsb + BOUT + ((d + HALF) << 2)) = pkf16(c0, c1);
  }
}

// ---------------------------------------------------------------------------
// Staging helper: input rows b0, b0+1 (channel's 14400 features) -> half2 LDS.
// ---------------------------------------------------------------------------
__device__ __forceinline__ void stage_x(char* ldsb, const void* __restrict__ x,
                                        int fdt, int ch, int b0) {
  const int t = threadIdx.x;
  if (fdt) {
    const ushort* r0 = (const ushort*)x + (size_t)b0 * 28800 + ch * 14400;
    const ushort* r1 = r0 + 28800;
    for (int c = t; c < 3600; c += NT) {
      const ushort4 a = ((const ushort4*)r0)[c];
      const ushort4 b = ((const ushort4*)r1)[c];
      uint4 u;
      u.x = pkf16(b2f(a.x), b2f(b.x));
      u.y = pkf16(b2f(a.y), b2f(b.y));
      u.z = pkf16(b2f(a.z), b2f(b.z));
      u.w = pkf16(b2f(a.w), b2f(b.w));
      ((uint4*)ldsb)[c] = u;
    }
  } else {
    const float* r0 = (const float*)x + (size_t)b0 * 28800 + ch * 14400;
    const float* r1 = r0 + 28800;
    for (int c = t; c < 3600; c += NT) {
      const float4 a = ((const float4*)r0)[c];
      const float4 b = ((const float4*)r1)[c];
      uint4 u;
      u.x = pkf16(a.x, b.x);
      u.y = pkf16(a.y, b.y);
      u.z = pkf16(a.z, b.z);
      u.w = pkf16(a.w, b.w);
      ((uint4*)ldsb)[c] = u;
    }
  }
}

// ---------------------------------------------------------------------------
// Fused network: block = (channel, batch-slice of 2), NT=1024 (16 waves/CU).
// LDS plan (bytes, half2 per feature): in@0 (57600) -> h0@57600 (28800);
// L1: h0@57600 -> h1@0 (14400); L2: h1@0 -> h2@14400 (7200); fc reads h2@14400.
// ---------------------------------------------------------------------------
__global__ __launch_bounds__(NT) void lcn_fused(
    const void* __restrict__ x, const unsigned int* __restrict__ pk,
    const float* __restrict__ pbias,
    const void* __restrict__ fcpw, const void* __restrict__ fcnw,
    const void* __restrict__ fcpb, const void* __restrict__ fcnb,
    const void* __restrict__ f3w, const void* __restrict__ f3b,
    float* __restrict__ y, int* __restrict__ flags, void* __restrict__ out) {
  __shared__ __align__(16) char ldsb[86400];
  __shared__ float red[NT / 64][4];
  __shared__ int sflag;
  const int t = threadIdx.x;
  const int ch = blockIdx.x & 1;
  const int b0 = (blockIdx.x >> 1) * 2;

  if (t == 0) sflag = flags[0];
  __syncthreads();
  const int fdt = sflag;

  stage_x(ldsb, x, fdt, ch, b0);
  __syncthreads();

  layer_run<0, 57600, D0>(ldsb, pk, pbias, 0 + ch * 180000, 0 + ch * D0);
  __syncthreads();
  layer_run<57600, 0, D1>(ldsb, pk, pbias, PKB_L1 + ch * 90000, 14400 + ch * D1);
  __syncthreads();
  layer_run<0, 14400, D2>(ldsb, pk, pbias, PKB_L2 + ch * 45000, 21600 + ch * D2);
  __syncthreads();

  // ---- fc: y[ch][o][b0..b0+1] = sum_d fw[o][d] * h2[d][.] ----
  {
    const void* fw = ch ? fcnw : fcpw;
    float a00 = 0.f, a01 = 0.f, a10 = 0.f, a11 = 0.f;
    for (int d = t; d < D2; d += NT) {
      const half2_t vv = *(const half2_t*)(ldsb + 14400 + (d << 2));
      const float v0 = (float)vv.x;
      const float v1 = (float)vv.y;
      const float w0 = fdt ? b2f(((const ushort*)fw)[d]) : ((const float*)fw)[d];
      const float w1 = fdt ? b2f(((const ushort*)fw)[D2 + d]) : ((const float*)fw)[D2 + d];
      a00 = fmaf(w0, v0, a00); a01 = fmaf(w0, v1, a01);
      a10 = fmaf(w1, v0, a10); a11 = fmaf(w1, v1, a11);
    }
#pragma unroll
    for (int off = 32; off > 0; off >>= 1) {
      a00 += __shfl_down(a00, off);
      a01 += __shfl_down(a01, off);
      a10 += __shfl_down(a10, off);
      a11 += __shfl_down(a11, off);
    }
    const int wave = t >> 6, lane = t & 63;
    if (lane == 0) {
      red[wave][0] = a00; red[wave][1] = a01; red[wave][2] = a10; red[wave][3] = a11;
    }
    __syncthreads();
    if (t == 0) {
      float s00 = 0.f, s01 = 0.f, s10 = 0.f, s11 = 0.f;
#pragma unroll
      for (int wv = 0; wv < NT / 64; ++wv) {
        s00 += red[wv][0]; s01 += red[wv][1]; s10 += red[wv][2]; s11 += red[wv][3];
      }
      atomicAdd(&y[(ch * 2 + 0) * 256 + b0], s00);
      atomicAdd(&y[(ch * 2 + 0) * 256 + b0 + 1], s01);
      atomicAdd(&y[(ch * 2 + 1) * 256 + b0], s10);
      atomicAdd(&y[(ch * 2 + 1) * 256 + b0 + 1], s11);
    }
  }

  // ---- last-done block computes the final combine (round-5-validated) ----
  __syncthreads();
  if (t == 0) {
    __threadfence();
    sflag = (atomicAdd(&flags[16], 1) == (int)gridDim.x - 1) ? 1 : 0;
  }
  __syncthreads();
  if (sflag && t < 256) {
    const int b = t;
    const float y0 = atomicAdd(&y[0 * 256 + b], 0.0f);
    const float y1 = atomicAdd(&y[1 * 256 + b], 0.0f);
    const float y2 = atomicAdd(&y[2 * 256 + b], 0.0f);
    const float y3 = atomicAdd(&y[3 * 256 + b], 0.0f);
    const float bp0v = fdt ? b2f(((const ushort*)fcpb)[0]) : ((const float*)fcpb)[0];
    const float bp1v = fdt ? b2f(((const ushort*)fcpb)[1]) : ((const float*)fcpb)[1];
    const float bn0v = fdt ? b2f(((const ushort*)fcnb)[0]) : ((const float*)fcnb)[0];
    const float bn1v = fdt ? b2f(((const ushort*)fcnb)[1]) : ((const float*)fcnb)[1];
    const float h0v = fmaxf(y0 + bp0v, 0.f);
    const float h1v = fmaxf(y1 + bp1v, 0.f);
    const float h2v = fmaxf(y2 + bn0v, 0.f);
    const float h3v = fmaxf(y3 + bn1v, 0.f);
#pragma unroll
    for (int o = 0; o < 2; ++o) {
      float w0, w1, w2, w3, bb;
      if (fdt) {
        const ushort* fp = (const ushort*)f3w;
        w0 = b2f(fp[o * 4 + 0]); w1 = b2f(fp[o * 4 + 1]);
        w2 = b2f(fp[o * 4 + 2]); w3 = b2f(fp[o * 4 + 3]);
        bb = b2f(((const ushort*)f3b)[o]);
      } else {
        const float* fp = (const float*)f3w;
        w0 = fp[o * 4 + 0]; w1 = fp[o * 4 + 1];
        w2 = fp[o * 4 + 2]; w3 = fp[o * 4 + 3];
        bb = ((const float*)f3b)[o];
      }
      float r = bb;
      r = fmaf(w0, h0v, r); r = fmaf(w1, h1v, r);
      r = fmaf(w2, h2v, r); r = fmaf(w3, h3v, r);
      if (fdt) ((ushort*)out)[b * 2 + o] = f2b(r);
      else     ((float*)out)[b * 2 + o] = r;
    }
  }
}

extern "C" void kernel_launch(void* const* d_in, const int* in_sizes, int n_in,
                              void* d_out, int out_size, void* d_ws, size_t ws_size,
                              hipStream_t stream) {
  const void* x    = d_in[0];
  const void* knn0 = d_in[1];
  const void* knn1 = d_in[2];
  const void* knn2 = d_in[3];
  const void* wp0  = d_in[4];  const void* bp0 = d_in[5];
  const void* wp1  = d_in[6];  const void* bp1 = d_in[7];
  const void* wp2  = d_in[8];  const void* bp2 = d_in[9];
  const void* fcpw = d_in[10]; const void* fcpb = d_in[11];
  const void* wn0  = d_in[12]; const void* bn0 = d_in[13];
  const void* wn1  = d_in[14]; const void* bn1 = d_in[15];
  const void* wn2  = d_in[16]; const void* bn2 = d_in[17];
  const void* fcnw = d_in[18]; const void* fcnb = d_in[19];
  const void* f3w  = d_in[20]; const void* f3b  = d_in[21];

  char* ws = (char*)d_ws;
  unsigned int* pk = (unsigned int*)(ws);         // 630000*4 = 2,520,000 B
  float* pbias = (float*)(ws + 2520000);          // 25200*4  =   100,800 B
  float* y     = (float*)(ws + 2620800);          // 1024*4   =     4,096 B
  int* flags   = (int*)(ws + 2624896);            // flags[0..1], flags[16]

  // 197 prepack blocks (128 dims x 2 khalves each) + 1 y-zero block
  prepack_kernel<<<198, 256, 0, stream>>>(x, knn0, knn1, knn2,
                                          wp0, bp0, wp1, bp1, wp2, bp2,
                                          wn0, bn0, wn1, bn1, wn2, bn2,
                                          pk, pbias, y, flags);

  lcn_fused<<<256, NT, 0, stream>>>(x, pk, pbias, fcpw, fcnw, fcpb, fcnb,
                                    f3w, f3b, y, flags, d_out);
}